// Round 8
// baseline (205.612 us; speedup 1.0000x reference)
//
#include <hip/hip_runtime.h>
#include <hip/hip_bf16.h>

// Problem constants (set_attention): B=4, Nq=Nk=2048, D_IN=512, H=8, HS=64
#define BB   4
#define NQ   2048
#define NKK  2048
#define DIN  512
#define NH   8
#define HS   64
#define HD   512  // NH*HS

typedef __hip_bfloat16 bf16;
typedef unsigned short ushort_t;
typedef __attribute__((ext_vector_type(8))) short short8;   // 8 bf16 (4 VGPRs)
typedef __attribute__((ext_vector_type(4))) float f32x4;    // MFMA 16x16 C/D
typedef __attribute__((ext_vector_type(16))) float f32x16;  // MFMA 32x32 C/D
typedef __attribute__((ext_vector_type(4))) unsigned u32x4;

__device__ __forceinline__ unsigned short f2bu(float x) {
  bf16 h = __float2bfloat16(x);
  return *(unsigned short*)&h;
}

// ---------------------------------------------------------------------------
// Kernel 0: weight transpose + bf16 convert.
// z<3:  W[512k][512n] f32 -> Wt_z[n][k] bf16   (64x64 tiles via LDS)
// z==3: Wh[512k][64n] f32 -> Wht[n][k] bf16
// ---------------------------------------------------------------------------
__global__ __launch_bounds__(256) void wtrans_kernel(
    const float* __restrict__ Wq, const float* __restrict__ Wk,
    const float* __restrict__ Wv, const float* __restrict__ Wh,
    ushort_t* __restrict__ Wt, ushort_t* __restrict__ Wht) {
  const int z = blockIdx.z;
  const float* src;
  ushort_t* dst;
  int S;  // source row length (n-dim)
  if (z < 3) {
    src = (z == 0) ? Wq : (z == 1) ? Wk : Wv;
    dst = Wt + (size_t)z * 512 * 512;
    S = 512;
  } else {
    if (blockIdx.y != 0) return;
    src = Wh;
    dst = Wht;
    S = 64;
  }
  const int k0 = blockIdx.x * 64;
  const int n0 = (z < 3) ? blockIdx.y * 64 : 0;

  __shared__ ushort_t Ls[64 * 72];
  const int tid = threadIdx.x;
  {
    int r = tid >> 2, cb = (tid & 3) * 16;
    const float* sp = src + (size_t)(k0 + r) * S + n0 + cb;
#pragma unroll
    for (int ii = 0; ii < 4; ++ii) {
      float4 f = *(const float4*)(sp + ii * 4);
      __align__(8) ushort_t t4[4] = {f2bu(f.x), f2bu(f.y), f2bu(f.z), f2bu(f.w)};
      *(uint2*)(&Ls[r * 72 + cb + ii * 4]) = *(uint2*)t4;
    }
  }
  __syncthreads();
  {
    int rr = tid >> 2, tb = (tid & 3) * 16;
    __align__(16) ushort_t tmp[16];
#pragma unroll
    for (int j = 0; j < 16; ++j) tmp[j] = Ls[(tb + j) * 72 + rr];
    ushort_t* dp = dst + (size_t)(n0 + rr) * 512 + k0 + tb;
    *(int4*)dp       = ((int4*)tmp)[0];
    *(int4*)(dp + 8) = ((int4*)tmp)[1];
  }
}

// ---------------------------------------------------------------------------
// Kernel 1: QKV projections, bf16 MFMA, double-buffered. Y = X @ W.
// Q is scaled by (1/sqrt(64)) * log2(e) so attention can use exp2 directly.
// ---------------------------------------------------------------------------
__global__ __launch_bounds__(256) void proj_kernel(
    const float* __restrict__ q, const float* __restrict__ k,
    const ushort_t* __restrict__ Wt, ushort_t* __restrict__ Qf,
    ushort_t* __restrict__ Kf, ushort_t* __restrict__ Vf) {
  const int z = blockIdx.z;
  const float* X = (z == 0) ? q : k;
  const ushort_t* Wz = Wt + (size_t)z * 512 * 512;
  ushort_t* Y = (z == 0) ? Qf : (z == 1) ? Kf : Vf;
  // fold 1/sqrt(64) AND log2(e) into Q (attn uses exp2)
  const float sc = (z == 0) ? 0.18033688011112042f : 1.0f;

  __shared__ ushort_t As[2 * 128 * 40];  // [buf][m][k]
  __shared__ ushort_t Bs[2 * 128 * 40];  // [buf][n][k]

  const int tid  = threadIdx.x;
  const int lane = tid & 63;
  const int w    = tid >> 6;
  const int quad = lane >> 4;
  const int c    = lane & 15;
  const int wm   = w >> 1, wn = w & 1;

  const int m0 = blockIdx.y * 128;
  const int n0 = blockIdx.x * 128;
  const int sm  = tid >> 1;
  const int skb = (tid & 1) * 16;

  float4 xa[4];
  int4 wb[2];
  auto load_t = [&](int k0) {
    const float* xp = X + (size_t)(m0 + sm) * DIN + k0 + skb;
    xa[0] = *(const float4*)(xp + 0);
    xa[1] = *(const float4*)(xp + 4);
    xa[2] = *(const float4*)(xp + 8);
    xa[3] = *(const float4*)(xp + 12);
    const ushort_t* wp = Wz + (size_t)(n0 + sm) * 512 + k0 + skb;
    wb[0] = *(const int4*)wp;
    wb[1] = *(const int4*)(wp + 8);
  };
  auto store_t = [&](int buf) {
    __align__(16) ushort_t ta[16];
#pragma unroll
    for (int ii = 0; ii < 4; ++ii) {
      ta[ii * 4 + 0] = f2bu(xa[ii].x);
      ta[ii * 4 + 1] = f2bu(xa[ii].y);
      ta[ii * 4 + 2] = f2bu(xa[ii].z);
      ta[ii * 4 + 3] = f2bu(xa[ii].w);
    }
    *(int4*)(&As[buf * 5120 + sm * 40 + skb])     = ((int4*)ta)[0];
    *(int4*)(&As[buf * 5120 + sm * 40 + skb + 8]) = ((int4*)ta)[1];
    *(int4*)(&Bs[buf * 5120 + sm * 40 + skb])     = wb[0];
    *(int4*)(&Bs[buf * 5120 + sm * 40 + skb + 8]) = wb[1];
  };

  f32x4 acc[4][4];
#pragma unroll
  for (int m = 0; m < 4; ++m)
#pragma unroll
    for (int n = 0; n < 4; ++n) acc[m][n] = (f32x4)0.0f;

  load_t(0);
  store_t(0);
  __syncthreads();

  for (int t = 0; t < 16; ++t) {
    const int cur = t & 1;
    if (t < 15) load_t((t + 1) * 32);
    const ushort_t* as = As + cur * 5120;
    const ushort_t* bs = Bs + cur * 5120;
    short8 af[4], bfr[4];
#pragma unroll
    for (int m = 0; m < 4; ++m)
      af[m] = *(const short8*)(&as[(wm * 64 + m * 16 + c) * 40 + quad * 8]);
#pragma unroll
    for (int n = 0; n < 4; ++n)
      bfr[n] = *(const short8*)(&bs[(wn * 64 + n * 16 + c) * 40 + quad * 8]);
#pragma unroll
    for (int m = 0; m < 4; ++m)
#pragma unroll
      for (int n = 0; n < 4; ++n)
        acc[m][n] = __builtin_amdgcn_mfma_f32_16x16x32_bf16(af[m], bfr[n], acc[m][n], 0, 0, 0);
    if (t < 15) store_t(cur ^ 1);
    __syncthreads();
  }

#pragma unroll
  for (int m = 0; m < 4; ++m)
#pragma unroll
    for (int n = 0; n < 4; ++n)
#pragma unroll
      for (int r = 0; r < 4; ++r) {
        int row = m0 + wm * 64 + m * 16 + quad * 4 + r;
        int col = n0 + wn * 64 + n * 16 + c;
        Y[(size_t)row * HD + col] = f2bu(acc[m][n][r] * sc);
      }
}

// ---------------------------------------------------------------------------
// Kernel 1b: V transpose. Vf[(b*2048+t)*512 + cc] -> Vt[(b*512+cc)*2048 + t].
// ---------------------------------------------------------------------------
__global__ __launch_bounds__(256) void vtrans_kernel(
    const ushort_t* __restrict__ Vf, ushort_t* __restrict__ Vt) {
  const int b  = blockIdx.z;
  const int t0 = blockIdx.x * 64;
  const int c0 = blockIdx.y * 64;
  __shared__ ushort_t Ls[64 * 72];
  const int tid = threadIdx.x;
  {
    int r = tid >> 2, cb = (tid & 3) * 16;
    const ushort_t* src = Vf + (size_t)(b * NQ + t0 + r) * HD + c0 + cb;
    *(int4*)(&Ls[r * 72 + cb])     = *(const int4*)src;
    *(int4*)(&Ls[r * 72 + cb + 8]) = *(const int4*)(src + 8);
  }
  __syncthreads();
  {
    int rr = tid >> 2, tb = (tid & 3) * 16;
    __align__(16) ushort_t tmp[16];
#pragma unroll
    for (int j = 0; j < 16; ++j) tmp[j] = Ls[(tb + j) * 72 + rr];
    ushort_t* dst = Vt + (size_t)(b * HD + c0 + rr) * NKK + t0 + tb;
    *(int4*)dst       = ((int4*)tmp)[0];
    *(int4*)(dst + 8) = ((int4*)tmp)[1];
  }
}

// ---------------------------------------------------------------------------
// Kernel 2: MFMA flash attention, v9 — v8 + phase-grouped tile body
// (2-stage in-wave pipeline).
//  - Per tile: QK(all 16 MFMA, 4 independent chains interleaved) ->
//    SM(kg0) -> SM(kg1) -> PV(all 16 MFMA).
//    SM(kg1) runs while QK pipe drains; PV pipe overlaps next tile's
//    vmcnt/ds_read/QK-issue phase. Removes the serial per-kg chain that
//    left the wave idle ~60% at 1 wave/SIMD (v8: 4818 cyc/tile measured).
//  - Everything else = v8: 1-wave blocks, zero barriers, counted vmcnt(16),
//    XOR-swizzled LDS + pre-swizzled global source, XCD-aware decode,
//    exp2 softmax (log2e folded into Q scale), T12 cvt_pk+permlane repack.
// ---------------------------------------------------------------------------
__global__ __launch_bounds__(64, 1) void attn_kernel(
    const ushort_t* __restrict__ Qf, const ushort_t* __restrict__ Kf,
    const ushort_t* __restrict__ Vt, ushort_t* __restrict__ CTX) {
  // XCD-aware decode: 1024 blocks, xcd = id & 7 (round-robin heuristic).
  const int id   = blockIdx.x;
  const int xcd  = id & 7;
  const int slot = id >> 3;                // 0..127 within xcd
  const int p    = xcd * 4 + (slot >> 5);  // panel 0..31
  const int qb   = slot & 31;              // q-block 0..31 (64 rows each)
  const int h    = p & 7;
  const int b    = p >> 3;

  __shared__ ushort_t Kt[2][4096];  // [buf][key][d] 16B slots, swizzled
  __shared__ ushort_t Vs[2][4096];  // [buf][d][key] 16B slots, swizzled

  const int lane = threadIdx.x & 63;
  const int ql   = lane & 31;     // q (and A-row / B-col) index
  const int hi   = lane >> 5;     // lane half

  const int q0 = qb * 64;  // wave owns q0 .. q0+63

  // Q as B operand: bq[qs][ks] = Q[q0+qs*32+ql][ks*16 + hi*8 .. +7]
  short8 bq[2][4];
#pragma unroll
  for (int qs = 0; qs < 2; ++qs) {
    const ushort_t* qp =
        Qf + (size_t)(b * NQ + q0 + qs * 32 + ql) * HD + h * HS + hi * 8;
#pragma unroll
    for (int ks = 0; ks < 4; ++ks) bq[qs][ks] = *(const short8*)(qp + ks * 16);
  }

  // Staging: single wave stages the full 64x64 tile (16 global_load_lds).
  const int sub  = lane >> 3;      // row within 8-row chunk == row & 7
  const int slt  = lane & 7;       // 16B slot within row
  const int csrc = slt ^ sub;      // pre-swizzled source column (16B units)
  const ushort_t* kp0 =
      Kf + (size_t)(b * NKK + sub) * HD + h * HS + csrc * 8;
  const ushort_t* vp0 =
      Vt + (size_t)((b * NH + h) * HS + sub) * NKK + csrc * 8;

  auto stage = [&](int buf, int kt) {
    const ushort_t* kp = kp0 + (size_t)kt * 64 * HD;
    const ushort_t* vp = vp0 + (size_t)kt * 64;
#pragma unroll
    for (int i = 0; i < 8; ++i) {
      __builtin_amdgcn_global_load_lds(
          (const __attribute__((address_space(1))) unsigned*)(kp + (size_t)i * 8 * HD),
          (__attribute__((address_space(3))) unsigned*)(&Kt[buf][i * 512]),
          16, 0, 0);
      __builtin_amdgcn_global_load_lds(
          (const __attribute__((address_space(1))) unsigned*)(vp + (size_t)i * 8 * NKK),
          (__attribute__((address_space(3))) unsigned*)(&Vs[buf][i * 512]),
          16, 0, 0);
    }
  };

  // Loop-invariant swizzled LDS byte offsets for the fragment reads.
  int koff[2][4], voff[2][4];
#pragma unroll
  for (int g = 0; g < 2; ++g) {
    const int row = g * 32 + ql;
#pragma unroll
    for (int ks = 0; ks < 4; ++ks) {
      koff[g][ks] = row * 64 + (((ks * 2 + hi) ^ (row & 7)) * 8);
      voff[g][ks] = koff[g][ks];  // same geometry for Vs
    }
  }

  f32x16 o[2][2];  // [qs][ng]
#pragma unroll
  for (int qs = 0; qs < 2; ++qs)
#pragma unroll
    for (int ng = 0; ng < 2; ++ng) o[qs][ng] = (f32x16)0.0f;
  float lsum[2] = {0.0f, 0.0f};

  stage(0, 0);

  for (int t = 0; t < NKK / 64; ++t) {
    const int buf = t & 1;
    if (t < NKK / 64 - 1) {
      stage(buf ^ 1, t + 1);
      // prev tile's 16 loads done; the 16 just issued stay in flight
      asm volatile("s_waitcnt vmcnt(16)" ::: "memory");
    } else {
      asm volatile("s_waitcnt vmcnt(0)" ::: "memory");
    }
    const ushort_t* kb = &Kt[buf][0];
    const ushort_t* vb = &Vs[buf][0];

    // ---- Phase 1: K fragments + ALL 16 QK^T MFMAs (4 indep chains) ----
    short8 ak[2][4];
#pragma unroll
    for (int kg = 0; kg < 2; ++kg)
#pragma unroll
      for (int ks = 0; ks < 4; ++ks)
        ak[kg][ks] = *(const short8*)(&kb[koff[kg][ks]]);

    f32x16 s00 = (f32x16)0.0f, s01 = (f32x16)0.0f;
    f32x16 s10 = (f32x16)0.0f, s11 = (f32x16)0.0f;
    __builtin_amdgcn_s_setprio(1);
#pragma unroll
    for (int ks = 0; ks < 4; ++ks) {
      s00 = __builtin_amdgcn_mfma_f32_32x32x16_bf16(ak[0][ks], bq[0][ks], s00, 0, 0, 0);
      s01 = __builtin_amdgcn_mfma_f32_32x32x16_bf16(ak[0][ks], bq[1][ks], s01, 0, 0, 0);
      s10 = __builtin_amdgcn_mfma_f32_32x32x16_bf16(ak[1][ks], bq[0][ks], s10, 0, 0, 0);
      s11 = __builtin_amdgcn_mfma_f32_32x32x16_bf16(ak[1][ks], bq[1][ks], s11, 0, 0, 0);
    }
    __builtin_amdgcn_s_setprio(0);

    // V fragments (needed only in phase 3; reads overlap the QK pipe).
    short8 bv[2][4];
#pragma unroll
    for (int ng = 0; ng < 2; ++ng)
#pragma unroll
      for (int ks = 0; ks < 4; ++ks)
        bv[ng][ks] = *(const short8*)(&vb[voff[ng][ks]]);

    // ---- Phase 2: softmax both kg (VALU; overlaps QK pipe drain) ----
    // paA = PV A-frags for qs0 (k-steps 0..3), paB for qs1.
    short8 paA[4], paB[4];
#pragma unroll
    for (int kg = 0; kg < 2; ++kg) {
#pragma unroll
      for (int qs = 0; qs < 2; ++qs) {
        const f32x16& sv = (kg == 0) ? (qs == 0 ? s00 : s01)
                                     : (qs == 0 ? s10 : s11);
        float p_[16];
#pragma unroll
        for (int r = 0; r < 16; ++r) p_[r] = __builtin_amdgcn_exp2f(sv[r]);
        {
          float a0 = p_[0] + p_[1], a1 = p_[2] + p_[3], a2 = p_[4] + p_[5], a3 = p_[6] + p_[7];
          float a4 = p_[8] + p_[9], a5 = p_[10] + p_[11], a6 = p_[12] + p_[13], a7 = p_[14] + p_[15];
          a0 += a1; a2 += a3; a4 += a5; a6 += a7;
          lsum[qs] += (a0 + a2) + (a4 + a6);
        }
#pragma unroll
        for (int sp = 0; sp < 2; ++sp) {
          unsigned wA, wB, wC, wD;
          asm("v_cvt_pk_bf16_f32 %0, %1, %2" : "=v"(wA) : "v"(p_[8 * sp + 0]), "v"(p_[8 * sp + 1]));
          asm("v_cvt_pk_bf16_f32 %0, %1, %2" : "=v"(wB) : "v"(p_[8 * sp + 2]), "v"(p_[8 * sp + 3]));
          asm("v_cvt_pk_bf16_f32 %0, %1, %2" : "=v"(wC) : "v"(p_[8 * sp + 4]), "v"(p_[8 * sp + 5]));
          asm("v_cvt_pk_bf16_f32 %0, %1, %2" : "=v"(wD) : "v"(p_[8 * sp + 6]), "v"(p_[8 * sp + 7]));
          asm("v_permlane32_swap_b32 %0, %1" : "+v"(wA), "+v"(wC));
          asm("v_permlane32_swap_b32 %0, %1" : "+v"(wB), "+v"(wD));
          u32x4 pw;
          pw.x = wA;  // j0,j1
          pw.y = wB;  // j2,j3
          pw.z = wC;  // j4,j5
          pw.w = wD;  // j6,j7
          if (qs == 0) paA[kg * 2 + sp] = __builtin_bit_cast(short8, pw);
          else         paB[kg * 2 + sp] = __builtin_bit_cast(short8, pw);
        }
      }
    }

    // ---- Phase 3: ALL 16 PV MFMAs (pipe overlaps next tile's loads) ----
    __builtin_amdgcn_s_setprio(1);
#pragma unroll
    for (int ks = 0; ks < 4; ++ks) {
      o[0][0] = __builtin_amdgcn_mfma_f32_32x32x16_bf16(paA[ks], bv[0][ks], o[0][0], 0, 0, 0);
      o[1][0] = __builtin_amdgcn_mfma_f32_32x32x16_bf16(paB[ks], bv[0][ks], o[1][0], 0, 0, 0);
      o[0][1] = __builtin_amdgcn_mfma_f32_32x32x16_bf16(paA[ks], bv[1][ks], o[0][1], 0, 0, 0);
      o[1][1] = __builtin_amdgcn_mfma_f32_32x32x16_bf16(paB[ks], bv[1][ks], o[1][1], 0, 0, 0);
    }
    __builtin_amdgcn_s_setprio(0);
  }

  // Denominator: lane + lane^32 cover all 2048 keys of column q.
  float inv[2];
#pragma unroll
  for (int qs = 0; qs < 2; ++qs) {
    float tot = lsum[qs] + __shfl_xor(lsum[qs], 32);
    inv[qs] = 1.0f / tot;
  }

  // O layout: row q = (reg&3)+8*(reg>>2)+4*hi, col d = ng*32 + ql.
#pragma unroll
  for (int qs = 0; qs < 2; ++qs)
#pragma unroll
    for (int r = 0; r < 16; ++r) {
      int qr = (r & 3) + 8 * (r >> 2) + 4 * hi;
      float iv = __shfl(inv[qs], qr);
      size_t base = (size_t)(b * NQ + q0 + qs * 32 + qr) * HD + h * HS + ql;
      CTX[base]      = f2bu(o[qs][0][r] * iv);
      CTX[base + 32] = f2bu(o[qs][1][r] * iv);
    }
}

// ---------------------------------------------------------------------------
// Kernel 3: out[8192,64] = CTX[8192,512] @ Wh[512,64], LDS-free MFMA.
// ---------------------------------------------------------------------------
__global__ __launch_bounds__(64) void outproj_kernel(
    const ushort_t* __restrict__ CTX, const ushort_t* __restrict__ Wht,
    float* __restrict__ out) {
  const int lane = threadIdx.x & 63;
  const int quad = lane >> 4, c = lane & 15;
  const int m0 = blockIdx.x * 16;

  f32x4 o[4];
#pragma unroll
  for (int n = 0; n < 4; ++n) o[n] = (f32x4)0.0f;

  const ushort_t* arow = CTX + (size_t)(m0 + c) * HD;
#pragma unroll 4
  for (int ks = 0; ks < 16; ++ks) {
    short8 a = *(const short8*)(arow + ks * 32 + quad * 8);
#pragma unroll
    for (int nd = 0; nd < 4; ++nd) {
      short8 bn = *(const short8*)(Wht + (size_t)(nd * 16 + c) * 512 + ks * 32 + quad * 8);
      o[nd] = __builtin_amdgcn_mfma_f32_16x16x32_bf16(a, bn, o[nd], 0, 0, 0);
    }
  }
#pragma unroll
  for (int nd = 0; nd < 4; ++nd)
#pragma unroll
    for (int r = 0; r < 4; ++r)
      out[(size_t)(m0 + quad * 4 + r) * HS + nd * 16 + c] = o[nd][r];
}

// ---------------------------------------------------------------------------
extern "C" void kernel_launch(void* const* d_in, const int* in_sizes, int n_in,
                              void* d_out, int out_size, void* d_ws,
                              size_t ws_size, hipStream_t stream) {
  const float* q  = (const float*)d_in[0];
  const float* k  = (const float*)d_in[1];
  const float* Wq = (const float*)d_in[2];
  const float* Wk = (const float*)d_in[3];
  const float* Wv = (const float*)d_in[4];
  const float* Wh = (const float*)d_in[5];
  float* out = (float*)d_out;

  // Workspace (bf16/ushort): Qf|Kf|Vt|CTX|Vf (each 8 MiB) + Wt (1.5 MiB) + Wht
  const size_t E = (size_t)BB * NQ * HD;
  ushort_t* ws  = (ushort_t*)d_ws;
  ushort_t* Qf  = ws;
  ushort_t* Kf  = Qf + E;
  ushort_t* Vt  = Kf + E;
  ushort_t* CTX = Vt + E;
  ushort_t* Vf  = CTX + E;
  ushort_t* Wt  = Vf + E;                      // 3 x 512 x 512
  ushort_t* Wht = Wt + (size_t)3 * 512 * 512;  // 64 x 512

  wtrans_kernel<<<dim3(8, 8, 4), 256, 0, stream>>>(Wq, Wk, Wv, Wh, Wt, Wht);
  proj_kernel<<<dim3(HD / 128, BB * NQ / 128, 3), 256, 0, stream>>>(
      q, k, Wt, Qf, Kf, Vf);
  vtrans_kernel<<<dim3(NKK / 64, HD / 64, BB), 256, 0, stream>>>(Vf, Vt);
  attn_kernel<<<dim3(32 * NH * BB), 64, 0, stream>>>(Qf, Kf, Vt, CTX);
  outproj_kernel<<<dim3(BB * NQ / 16), 64, 0, stream>>>(CTX, Wht, out);
}

// Round 9
// 191.691 us; speedup vs baseline: 1.0726x; 1.0726x over previous
//
#include <hip/hip_runtime.h>
#include <hip/hip_bf16.h>

// Problem constants (set_attention): B=4, Nq=Nk=2048, D_IN=512, H=8, HS=64
#define BB   4
#define NQ   2048
#define NKK  2048
#define DIN  512
#define NH   8
#define HS   64
#define HD   512  // NH*HS

typedef __hip_bfloat16 bf16;
typedef unsigned short ushort_t;
typedef __attribute__((ext_vector_type(8))) short short8;   // 8 bf16 (4 VGPRs)
typedef __attribute__((ext_vector_type(4))) float f32x4;    // MFMA 16x16 C/D
typedef __attribute__((ext_vector_type(16))) float f32x16;  // MFMA 32x32 C/D
typedef __attribute__((ext_vector_type(4))) unsigned u32x4;

__device__ __forceinline__ unsigned short f2bu(float x) {
  bf16 h = __float2bfloat16(x);
  return *(unsigned short*)&h;
}

// ---------------------------------------------------------------------------
// Kernel 0: weight transpose + bf16 convert.
// z<3:  W[512k][512n] f32 -> Wt_z[n][k] bf16   (64x64 tiles via LDS)
// z==3: Wh[512k][64n] f32 -> Wht[n][k] bf16
// ---------------------------------------------------------------------------
__global__ __launch_bounds__(256) void wtrans_kernel(
    const float* __restrict__ Wq, const float* __restrict__ Wk,
    const float* __restrict__ Wv, const float* __restrict__ Wh,
    ushort_t* __restrict__ Wt, ushort_t* __restrict__ Wht) {
  const int z = blockIdx.z;
  const float* src;
  ushort_t* dst;
  int S;  // source row length (n-dim)
  if (z < 3) {
    src = (z == 0) ? Wq : (z == 1) ? Wk : Wv;
    dst = Wt + (size_t)z * 512 * 512;
    S = 512;
  } else {
    if (blockIdx.y != 0) return;
    src = Wh;
    dst = Wht;
    S = 64;
  }
  const int k0 = blockIdx.x * 64;
  const int n0 = (z < 3) ? blockIdx.y * 64 : 0;

  __shared__ ushort_t Ls[64 * 72];
  const int tid = threadIdx.x;
  {
    int r = tid >> 2, cb = (tid & 3) * 16;
    const float* sp = src + (size_t)(k0 + r) * S + n0 + cb;
#pragma unroll
    for (int ii = 0; ii < 4; ++ii) {
      float4 f = *(const float4*)(sp + ii * 4);
      __align__(8) ushort_t t4[4] = {f2bu(f.x), f2bu(f.y), f2bu(f.z), f2bu(f.w)};
      *(uint2*)(&Ls[r * 72 + cb + ii * 4]) = *(uint2*)t4;
    }
  }
  __syncthreads();
  {
    int rr = tid >> 2, tb = (tid & 3) * 16;
    __align__(16) ushort_t tmp[16];
#pragma unroll
    for (int j = 0; j < 16; ++j) tmp[j] = Ls[(tb + j) * 72 + rr];
    ushort_t* dp = dst + (size_t)(n0 + rr) * 512 + k0 + tb;
    *(int4*)dp       = ((int4*)tmp)[0];
    *(int4*)(dp + 8) = ((int4*)tmp)[1];
  }
}

// ---------------------------------------------------------------------------
// Kernel 1: QKV projections, bf16 MFMA, double-buffered. Y = X @ W.
// Q scaled by (1/sqrt(64))*log2(e) so attention uses exp2 directly.
// z==2 (V) writes DIRECTLY TRANSPOSED into Vt[(b*512+col)*2048 + t]
// (4 consecutive t per lane -> aligned 8B uint2 stores), killing the
// separate vtrans kernel and its 32 MB HBM round-trip.
// ---------------------------------------------------------------------------
__global__ __launch_bounds__(256) void proj_kernel(
    const float* __restrict__ q, const float* __restrict__ k,
    const ushort_t* __restrict__ Wt, ushort_t* __restrict__ Qf,
    ushort_t* __restrict__ Kf, ushort_t* __restrict__ Vt) {
  const int z = blockIdx.z;
  const float* X = (z == 0) ? q : k;
  const ushort_t* Wz = Wt + (size_t)z * 512 * 512;
  // fold 1/sqrt(64) AND log2(e) into Q (attn uses exp2)
  const float sc = (z == 0) ? 0.18033688011112042f : 1.0f;

  __shared__ ushort_t As[2 * 128 * 40];  // [buf][m][k]
  __shared__ ushort_t Bs[2 * 128 * 40];  // [buf][n][k]

  const int tid  = threadIdx.x;
  const int lane = tid & 63;
  const int w    = tid >> 6;
  const int quad = lane >> 4;
  const int c    = lane & 15;
  const int wm   = w >> 1, wn = w & 1;

  const int m0 = blockIdx.y * 128;
  const int n0 = blockIdx.x * 128;
  const int sm  = tid >> 1;
  const int skb = (tid & 1) * 16;

  float4 xa[4];
  int4 wb[2];
  auto load_t = [&](int k0) {
    const float* xp = X + (size_t)(m0 + sm) * DIN + k0 + skb;
    xa[0] = *(const float4*)(xp + 0);
    xa[1] = *(const float4*)(xp + 4);
    xa[2] = *(const float4*)(xp + 8);
    xa[3] = *(const float4*)(xp + 12);
    const ushort_t* wp = Wz + (size_t)(n0 + sm) * 512 + k0 + skb;
    wb[0] = *(const int4*)wp;
    wb[1] = *(const int4*)(wp + 8);
  };
  auto store_t = [&](int buf) {
    __align__(16) ushort_t ta[16];
#pragma unroll
    for (int ii = 0; ii < 4; ++ii) {
      ta[ii * 4 + 0] = f2bu(xa[ii].x);
      ta[ii * 4 + 1] = f2bu(xa[ii].y);
      ta[ii * 4 + 2] = f2bu(xa[ii].z);
      ta[ii * 4 + 3] = f2bu(xa[ii].w);
    }
    *(int4*)(&As[buf * 5120 + sm * 40 + skb])     = ((int4*)ta)[0];
    *(int4*)(&As[buf * 5120 + sm * 40 + skb + 8]) = ((int4*)ta)[1];
    *(int4*)(&Bs[buf * 5120 + sm * 40 + skb])     = wb[0];
    *(int4*)(&Bs[buf * 5120 + sm * 40 + skb + 8]) = wb[1];
  };

  f32x4 acc[4][4];
#pragma unroll
  for (int m = 0; m < 4; ++m)
#pragma unroll
    for (int n = 0; n < 4; ++n) acc[m][n] = (f32x4)0.0f;

  load_t(0);
  store_t(0);
  __syncthreads();

  for (int t = 0; t < 16; ++t) {
    const int cur = t & 1;
    if (t < 15) load_t((t + 1) * 32);
    const ushort_t* as = As + cur * 5120;
    const ushort_t* bs = Bs + cur * 5120;
    short8 af[4], bfr[4];
#pragma unroll
    for (int m = 0; m < 4; ++m)
      af[m] = *(const short8*)(&as[(wm * 64 + m * 16 + c) * 40 + quad * 8]);
#pragma unroll
    for (int n = 0; n < 4; ++n)
      bfr[n] = *(const short8*)(&bs[(wn * 64 + n * 16 + c) * 40 + quad * 8]);
#pragma unroll
    for (int m = 0; m < 4; ++m)
#pragma unroll
      for (int n = 0; n < 4; ++n)
        acc[m][n] = __builtin_amdgcn_mfma_f32_16x16x32_bf16(af[m], bfr[n], acc[m][n], 0, 0, 0);
    if (t < 15) store_t(cur ^ 1);
    __syncthreads();
  }

  if (z != 2) {
    ushort_t* Y = (z == 0) ? Qf : Kf;
#pragma unroll
    for (int m = 0; m < 4; ++m)
#pragma unroll
      for (int n = 0; n < 4; ++n)
#pragma unroll
        for (int r = 0; r < 4; ++r) {
          int row = m0 + wm * 64 + m * 16 + quad * 4 + r;
          int col = n0 + wn * 64 + n * 16 + c;
          Y[(size_t)row * HD + col] = f2bu(acc[m][n][r] * sc);
        }
  } else {
    // V: transposed write. rows m0.. are b*2048+t; 4 consecutive t per lane.
#pragma unroll
    for (int m = 0; m < 4; ++m)
#pragma unroll
      for (int n = 0; n < 4; ++n) {
        int row0 = m0 + wm * 64 + m * 16 + quad * 4;  // +r, same b for all r
        int col  = n0 + wn * 64 + n * 16 + c;
        int bb   = row0 >> 11;         // batch
        int t0   = row0 & 2047;        // token (multiple of 4 -> 8B aligned)
        __align__(8) ushort_t t4[4] = {f2bu(acc[m][n][0]), f2bu(acc[m][n][1]),
                                       f2bu(acc[m][n][2]), f2bu(acc[m][n][3])};
        *(uint2*)(&Vt[((size_t)bb * HD + col) * NKK + t0]) = *(uint2*)t4;
      }
  }
}

// ---------------------------------------------------------------------------
// Kernel 2: MFMA flash attention, v10 = v8 (best measured, 64.2 us) with
// s_setprio removed (m190: setprio null-to-negative outside phase-split
// schedules; isolated A/B via this dispatch's dur).
//  - 64 threads/block, grid 1024 (XCD-swizzled): 1-wave blocks, private
//    32 KB K/V double buffer, zero barriers.
//  - Counted vmcnt(16): next tile's 16 global_load_lds stay in flight.
//  - All 16 K/V ds_read_b128 issued back-to-back at tile start.
//  - Each K/V fragment feeds 2 MFMAs (two 32-row q-subtiles).
//  - exp2 softmax (log2e folded into Q scale); T12 cvt_pk+permlane repack.
//  - XOR-swizzled LDS (slot ^ (row&7)) with pre-swizzled global source.
// ---------------------------------------------------------------------------
__global__ __launch_bounds__(64, 1) void attn_kernel(
    const ushort_t* __restrict__ Qf, const ushort_t* __restrict__ Kf,
    const ushort_t* __restrict__ Vt, ushort_t* __restrict__ CTX) {
  // XCD-aware decode: 1024 blocks, xcd = id & 7 (round-robin heuristic).
  const int id   = blockIdx.x;
  const int xcd  = id & 7;
  const int slot = id >> 3;                // 0..127 within xcd
  const int p    = xcd * 4 + (slot >> 5);  // panel 0..31
  const int qb   = slot & 31;              // q-block 0..31 (64 rows each)
  const int h    = p & 7;
  const int b    = p >> 3;

  __shared__ ushort_t Kt[2][4096];  // [buf][key][d] 16B slots, swizzled
  __shared__ ushort_t Vs[2][4096];  // [buf][d][key] 16B slots, swizzled

  const int lane = threadIdx.x & 63;
  const int ql   = lane & 31;     // q (and A-row / B-col) index
  const int hi   = lane >> 5;     // lane half

  const int q0 = qb * 64;  // wave owns q0 .. q0+63

  // Q as B operand: bq[qs][ks] = Q[q0+qs*32+ql][ks*16 + hi*8 .. +7]
  short8 bq[2][4];
#pragma unroll
  for (int qs = 0; qs < 2; ++qs) {
    const ushort_t* qp =
        Qf + (size_t)(b * NQ + q0 + qs * 32 + ql) * HD + h * HS + hi * 8;
#pragma unroll
    for (int ks = 0; ks < 4; ++ks) bq[qs][ks] = *(const short8*)(qp + ks * 16);
  }

  // Staging: single wave stages the full 64x64 tile (16 global_load_lds).
  const int sub  = lane >> 3;      // row within 8-row chunk == row & 7
  const int slt  = lane & 7;       // 16B slot within row
  const int csrc = slt ^ sub;      // pre-swizzled source column (16B units)
  const ushort_t* kp0 =
      Kf + (size_t)(b * NKK + sub) * HD + h * HS + csrc * 8;
  const ushort_t* vp0 =
      Vt + (size_t)((b * NH + h) * HS + sub) * NKK + csrc * 8;

  auto stage = [&](int buf, int kt) {
    const ushort_t* kp = kp0 + (size_t)kt * 64 * HD;
    const ushort_t* vp = vp0 + (size_t)kt * 64;
#pragma unroll
    for (int i = 0; i < 8; ++i) {
      __builtin_amdgcn_global_load_lds(
          (const __attribute__((address_space(1))) unsigned*)(kp + (size_t)i * 8 * HD),
          (__attribute__((address_space(3))) unsigned*)(&Kt[buf][i * 512]),
          16, 0, 0);
      __builtin_amdgcn_global_load_lds(
          (const __attribute__((address_space(1))) unsigned*)(vp + (size_t)i * 8 * NKK),
          (__attribute__((address_space(3))) unsigned*)(&Vs[buf][i * 512]),
          16, 0, 0);
    }
  };

  f32x16 o[2][2];  // [qs][ng]
#pragma unroll
  for (int qs = 0; qs < 2; ++qs)
#pragma unroll
    for (int ng = 0; ng < 2; ++ng) o[qs][ng] = (f32x16)0.0f;
  float lsum[2] = {0.0f, 0.0f};

  stage(0, 0);

  for (int t = 0; t < NKK / 64; ++t) {
    const int buf = t & 1;
    if (t < NKK / 64 - 1) {
      stage(buf ^ 1, t + 1);
      // prev tile's 16 loads done; the 16 just issued stay in flight
      asm volatile("s_waitcnt vmcnt(16)" ::: "memory");
    } else {
      asm volatile("s_waitcnt vmcnt(0)" ::: "memory");
    }
    const ushort_t* kb = &Kt[buf][0];
    const ushort_t* vb = &Vs[buf][0];

    // Prefetch ALL fragments for this tile: 16 back-to-back ds_read_b128.
    short8 ak[2][4], bv[2][4];
#pragma unroll
    for (int kg = 0; kg < 2; ++kg) {
      const int krow = kg * 32 + ql;
#pragma unroll
      for (int ks = 0; ks < 4; ++ks)
        ak[kg][ks] = *(const short8*)(&kb[krow * 64 + (((ks * 2 + hi) ^ (krow & 7)) * 8)]);
    }
#pragma unroll
    for (int ng = 0; ng < 2; ++ng) {
      const int vrow = ng * 32 + ql;
#pragma unroll
      for (int ks = 0; ks < 4; ++ks)
        bv[ng][ks] = *(const short8*)(&vb[vrow * 64 + (((ks * 2 + hi) ^ (vrow & 7)) * 8)]);
    }

#pragma unroll
    for (int kg = 0; kg < 2; ++kg) {
      // S^T = K @ Q^T for both q-subtiles, sharing each K fragment.
      f32x16 s[2];
      s[0] = (f32x16)0.0f;
      s[1] = (f32x16)0.0f;
#pragma unroll
      for (int ks = 0; ks < 4; ++ks) {
        s[0] = __builtin_amdgcn_mfma_f32_32x32x16_bf16(ak[kg][ks], bq[0][ks], s[0], 0, 0, 0);
        s[1] = __builtin_amdgcn_mfma_f32_32x32x16_bf16(ak[kg][ks], bq[1][ks], s[1], 0, 0, 0);
      }

      // Softmax (no-max, exp2) + in-register repack to PV A-fragments.
      short8 pa[2][2];  // [qs][sp]
#pragma unroll
      for (int qs = 0; qs < 2; ++qs) {
        float p_[16];
#pragma unroll
        for (int r = 0; r < 16; ++r) p_[r] = __builtin_amdgcn_exp2f(s[qs][r]);
        {
          float a0 = p_[0] + p_[1], a1 = p_[2] + p_[3], a2 = p_[4] + p_[5], a3 = p_[6] + p_[7];
          float a4 = p_[8] + p_[9], a5 = p_[10] + p_[11], a6 = p_[12] + p_[13], a7 = p_[14] + p_[15];
          a0 += a1; a2 += a3; a4 += a5; a6 += a7;
          lsum[qs] += (a0 + a2) + (a4 + a6);
        }
#pragma unroll
        for (int sp = 0; sp < 2; ++sp) {
          unsigned wA, wB, wC, wD;
          asm("v_cvt_pk_bf16_f32 %0, %1, %2" : "=v"(wA) : "v"(p_[8 * sp + 0]), "v"(p_[8 * sp + 1]));
          asm("v_cvt_pk_bf16_f32 %0, %1, %2" : "=v"(wB) : "v"(p_[8 * sp + 2]), "v"(p_[8 * sp + 3]));
          asm("v_cvt_pk_bf16_f32 %0, %1, %2" : "=v"(wC) : "v"(p_[8 * sp + 4]), "v"(p_[8 * sp + 5]));
          asm("v_cvt_pk_bf16_f32 %0, %1, %2" : "=v"(wD) : "v"(p_[8 * sp + 6]), "v"(p_[8 * sp + 7]));
          asm("v_permlane32_swap_b32 %0, %1" : "+v"(wA), "+v"(wC));
          asm("v_permlane32_swap_b32 %0, %1" : "+v"(wB), "+v"(wD));
          u32x4 pw;
          pw.x = wA;  // j0,j1
          pw.y = wB;  // j2,j3
          pw.z = wC;  // j4,j5
          pw.w = wD;  // j6,j7
          pa[qs][sp] = __builtin_bit_cast(short8, pw);
        }
      }

      // O += P @ V : each V fragment feeds both q-subtiles.
#pragma unroll
      for (int sp = 0; sp < 2; ++sp) {
        const int ks = kg * 2 + sp;
#pragma unroll
        for (int ng = 0; ng < 2; ++ng) {
          o[0][ng] = __builtin_amdgcn_mfma_f32_32x32x16_bf16(pa[0][sp], bv[ng][ks], o[0][ng], 0, 0, 0);
          o[1][ng] = __builtin_amdgcn_mfma_f32_32x32x16_bf16(pa[1][sp], bv[ng][ks], o[1][ng], 0, 0, 0);
        }
      }
    }
  }

  // Denominator: lane + lane^32 cover all 2048 keys of column q.
  float inv[2];
#pragma unroll
  for (int qs = 0; qs < 2; ++qs) {
    float tot = lsum[qs] + __shfl_xor(lsum[qs], 32);
    inv[qs] = 1.0f / tot;
  }

  // O layout: row q = (reg&3)+8*(reg>>2)+4*hi, col d = ng*32 + ql.
#pragma unroll
  for (int qs = 0; qs < 2; ++qs)
#pragma unroll
    for (int r = 0; r < 16; ++r) {
      int qr = (r & 3) + 8 * (r >> 2) + 4 * hi;
      float iv = __shfl(inv[qs], qr);
      size_t base = (size_t)(b * NQ + q0 + qs * 32 + qr) * HD + h * HS + ql;
      CTX[base]      = f2bu(o[qs][0][r] * iv);
      CTX[base + 32] = f2bu(o[qs][1][r] * iv);
    }
}

// ---------------------------------------------------------------------------
// Kernel 3: out[8192,64] = CTX[8192,512] @ Wh[512,64], LDS-free MFMA.
// ---------------------------------------------------------------------------
__global__ __launch_bounds__(64) void outproj_kernel(
    const ushort_t* __restrict__ CTX, const ushort_t* __restrict__ Wht,
    float* __restrict__ out) {
  const int lane = threadIdx.x & 63;
  const int quad = lane >> 4, c = lane & 15;
  const int m0 = blockIdx.x * 16;

  f32x4 o[4];
#pragma unroll
  for (int n = 0; n < 4; ++n) o[n] = (f32x4)0.0f;

  const ushort_t* arow = CTX + (size_t)(m0 + c) * HD;
#pragma unroll 4
  for (int ks = 0; ks < 16; ++ks) {
    short8 a = *(const short8*)(arow + ks * 32 + quad * 8);
#pragma unroll
    for (int nd = 0; nd < 4; ++nd) {
      short8 bn = *(const short8*)(Wht + (size_t)(nd * 16 + c) * 512 + ks * 32 + quad * 8);
      o[nd] = __builtin_amdgcn_mfma_f32_16x16x32_bf16(a, bn, o[nd], 0, 0, 0);
    }
  }
#pragma unroll
  for (int nd = 0; nd < 4; ++nd)
#pragma unroll
    for (int r = 0; r < 4; ++r)
      out[(size_t)(m0 + quad * 4 + r) * HS + nd * 16 + c] = o[nd][r];
}

// ---------------------------------------------------------------------------
extern "C" void kernel_launch(void* const* d_in, const int* in_sizes, int n_in,
                              void* d_out, int out_size, void* d_ws,
                              size_t ws_size, hipStream_t stream) {
  const float* q  = (const float*)d_in[0];
  const float* k  = (const float*)d_in[1];
  const float* Wq = (const float*)d_in[2];
  const float* Wk = (const float*)d_in[3];
  const float* Wv = (const float*)d_in[4];
  const float* Wh = (const float*)d_in[5];
  float* out = (float*)d_out;

  // Workspace (bf16/ushort): Qf|Kf|Vt|CTX|(unused) + Wt (1.5 MiB) + Wht
  const size_t E = (size_t)BB * NQ * HD;
  ushort_t* ws  = (ushort_t*)d_ws;
  ushort_t* Qf  = ws;
  ushort_t* Kf  = Qf + E;
  ushort_t* Vt  = Kf + E;
  ushort_t* CTX = Vt + E;
  ushort_t* Vf  = CTX + E;                     // unused (kept for layout)
  ushort_t* Wt  = Vf + E;                      // 3 x 512 x 512
  ushort_t* Wht = Wt + (size_t)3 * 512 * 512;  // 64 x 512

  wtrans_kernel<<<dim3(8, 8, 4), 256, 0, stream>>>(Wq, Wk, Wv, Wh, Wt, Wht);
  proj_kernel<<<dim3(HD / 128, BB * NQ / 128, 3), 256, 0, stream>>>(
      q, k, Wt, Qf, Kf, Vt);
  attn_kernel<<<dim3(32 * NH * BB), 64, 0, stream>>>(Qf, Kf, Vt, CTX);
  outproj_kernel<<<dim3(BB * NQ / 16), 64, 0, stream>>>(CTX, Wht, out);
}